// Round 5
// baseline (253.312 us; speedup 1.0000x reference)
//
#include <hip/hip_runtime.h>
#include <math.h>

// out[b,c,n] = softmax_n(max_c x[b,c,n]) * x[b,c,n]   (x: [256,64,2048] fp32)
//
// R7: all prior max-phase variants read with strided wave footprints (1KB
// line, then 8KB/32KB jump) and never exceeded ~3 TB/s, while this box
// streams writes at 6.7 TB/s (poison fills) and copies at 6.3 TB/s. This
// version makes each wave a contiguous streamer: wave w owns 4 CONSECUTIVE
// channels = one 32KB sequential region (block = 128KB), with 8 independent
// float4 accumulators (col position within the 8KB channel row selects the
// accumulator). Partials combine in LDS, staged at out[b,{0,16,32,48},:];
// softmax consolidates+replicates in place; mul kernel consumes race-free.
// No workspace (d_ws poison fills are unconditional harness overhead anyway).

#define B_DIM 256
#define C_DIM 64
#define N_DIM 2048
#define COLS4 (N_DIM / 4)          // 512 float4 columns per row
#define ROW4  (C_DIM * COLS4)      // 32768 float4 per batch row

// ---------------- K1: partial max over channel-quarters ----------------
// 1024 blocks = 256 rows x 4 quarters, 256 threads (4 waves).
// Wave w streams channels q*16+w*4 .. +3 (32KB contiguous). Lane l, position
// i in the 8KB channel row -> column i*64+l -> accumulator m[i].
// Result: out[b, q*16, :] = max over this quarter's 16 channels.
__global__ __launch_bounds__(256)
void max_kernel(const float* __restrict__ x, float* __restrict__ out) {
    const int bid  = blockIdx.x;
    const int b    = bid >> 2;
    const int q    = bid & 3;
    const int t    = threadIdx.x;
    const int w    = t >> 6;                 // 0..3
    const int lane = t & 63;

    const float4* __restrict__ xb =
        (const float4*)x + (size_t)b * ROW4 + (size_t)(q * 16 + w * 4) * COLS4;

    float4 m[8];
    #pragma unroll
    for (int i = 0; i < 8; ++i)
        m[i] = make_float4(-INFINITY, -INFINITY, -INFINITY, -INFINITY);

    #pragma unroll 2
    for (int c = 0; c < 4; ++c) {            // 4 consecutive channels
        float4 v[8];
        #pragma unroll
        for (int i = 0; i < 8; ++i)          // 8 independent 1KB wave-loads
            v[i] = xb[(size_t)c * COLS4 + (i << 6) + lane];
        #pragma unroll
        for (int i = 0; i < 8; ++i) {
            m[i].x = fmaxf(m[i].x, v[i].x);
            m[i].y = fmaxf(m[i].y, v[i].y);
            m[i].z = fmaxf(m[i].z, v[i].z);
            m[i].w = fmaxf(m[i].w, v[i].w);
        }
    }

    __shared__ float4 pm[4][8][64];          // 32 KB
    #pragma unroll
    for (int i = 0; i < 8; ++i) pm[w][i][lane] = m[i];
    __syncthreads();

    // combine 4 waves, write the quarter-partial to out[b, q*16, :]
    float4* og = (float4*)out + (size_t)b * ROW4 + (size_t)(q * 16) * COLS4;
    #pragma unroll
    for (int k = 0; k < 2; ++k) {
        const int j = t + (k << 8);          // 0..511
        const int i = j >> 6, l = j & 63;
        float4 a0 = pm[0][i][l], a1 = pm[1][i][l];
        float4 a2 = pm[2][i][l], a3 = pm[3][i][l];
        float4 r;
        r.x = fmaxf(fmaxf(a0.x, a1.x), fmaxf(a2.x, a3.x));
        r.y = fmaxf(fmaxf(a0.y, a1.y), fmaxf(a2.y, a3.y));
        r.z = fmaxf(fmaxf(a0.z, a1.z), fmaxf(a2.z, a3.z));
        r.w = fmaxf(fmaxf(a0.w, a1.w), fmaxf(a2.w, a3.w));
        og[j] = r;
    }
}

// ---------------- K2: gate = softmax(max of 4 partials), replicate ----------
// 256 blocks x 256 threads (4 waves), thread t owns columns t and t+256.
// Reads the 4 quarter-partials at channels {0,16,32,48}, consolidates,
// softmaxes, writes the gate back to those same 4 slots (read by K3).
__global__ __launch_bounds__(256)
void softmax_kernel(float* __restrict__ out) {
    const int b    = blockIdx.x;
    const int t    = threadIdx.x;
    const int lane = t & 63;
    const int wid  = t >> 6;                 // 0..3
    __shared__ float sred[8];

    float4* ob = (float4*)out + (size_t)b * ROW4;

    float4 a0, a1;
    {
        float4 p0 = ob[t];
        float4 p1 = ob[(size_t)16 * COLS4 + t];
        float4 p2 = ob[(size_t)32 * COLS4 + t];
        float4 p3 = ob[(size_t)48 * COLS4 + t];
        a0.x = fmaxf(fmaxf(p0.x, p1.x), fmaxf(p2.x, p3.x));
        a0.y = fmaxf(fmaxf(p0.y, p1.y), fmaxf(p2.y, p3.y));
        a0.z = fmaxf(fmaxf(p0.z, p1.z), fmaxf(p2.z, p3.z));
        a0.w = fmaxf(fmaxf(p0.w, p1.w), fmaxf(p2.w, p3.w));
        p0 = ob[t + 256];
        p1 = ob[(size_t)16 * COLS4 + t + 256];
        p2 = ob[(size_t)32 * COLS4 + t + 256];
        p3 = ob[(size_t)48 * COLS4 + t + 256];
        a1.x = fmaxf(fmaxf(p0.x, p1.x), fmaxf(p2.x, p3.x));
        a1.y = fmaxf(fmaxf(p0.y, p1.y), fmaxf(p2.y, p3.y));
        a1.z = fmaxf(fmaxf(p0.z, p1.z), fmaxf(p2.z, p3.z));
        a1.w = fmaxf(fmaxf(p0.w, p1.w), fmaxf(p2.w, p3.w));
    }

    float tm = fmaxf(fmaxf(fmaxf(a0.x, a0.y), fmaxf(a0.z, a0.w)),
                     fmaxf(fmaxf(a1.x, a1.y), fmaxf(a1.z, a1.w)));
    #pragma unroll
    for (int off = 32; off > 0; off >>= 1)
        tm = fmaxf(tm, __shfl_down(tm, off, 64));
    if (lane == 0) sred[wid] = tm;
    __syncthreads();
    const float M = fmaxf(fmaxf(sred[0], sred[1]), fmaxf(sred[2], sred[3]));

    float4 e0, e1;
    e0.x = __expf(a0.x - M); e0.y = __expf(a0.y - M);
    e0.z = __expf(a0.z - M); e0.w = __expf(a0.w - M);
    e1.x = __expf(a1.x - M); e1.y = __expf(a1.y - M);
    e1.z = __expf(a1.z - M); e1.w = __expf(a1.w - M);
    float ts = ((e0.x + e0.y) + (e0.z + e0.w)) + ((e1.x + e1.y) + (e1.z + e1.w));
    #pragma unroll
    for (int off = 32; off > 0; off >>= 1)
        ts += __shfl_down(ts, off, 64);
    if (lane == 0) sred[4 + wid] = ts;
    __syncthreads();
    const float inv = 1.0f / ((sred[4] + sred[5]) + (sred[6] + sred[7]));

    float4 g0, g1;
    g0.x = e0.x * inv; g0.y = e0.y * inv; g0.z = e0.z * inv; g0.w = e0.w * inv;
    g1.x = e1.x * inv; g1.y = e1.y * inv; g1.z = e1.z * inv; g1.w = e1.w * inv;
    #pragma unroll
    for (int g = 0; g < 4; ++g) {
        ob[(size_t)(g * 16) * COLS4 + t]       = g0;
        ob[(size_t)(g * 16) * COLS4 + t + 256] = g1;
    }
}

// ---------------- K3: out = gate * x ----------------
// 1024 blocks = 256 rows x 4 channel-groups (16 channels each), 512 threads.
// Each block reads ITS gate copy (channel g*16, the first it overwrites).
__global__ __launch_bounds__(512)
void mul_kernel(const float* __restrict__ x, float* __restrict__ out) {
    const int bid = blockIdx.x;
    const int b   = bid >> 2;
    const int g   = bid & 3;
    const int col = threadIdx.x;             // 0..511

    const size_t rbase = (size_t)b * ROW4;
    const float4* __restrict__ x4 = (const float4*)x + rbase;
    float4* o4 = (float4*)out + rbase;

    const int cbase = g * 16;
    const float4 gv = o4[(size_t)cbase * COLS4 + col];   // this block's copy
    __syncthreads();                          // all reads before any write

    #pragma unroll 4
    for (int c = 0; c < 16; ++c) {
        const size_t idx = (size_t)(cbase + c) * COLS4 + col;
        float4 v = x4[idx];
        float4 o;
        o.x = v.x * gv.x; o.y = v.y * gv.y;
        o.z = v.z * gv.z; o.w = v.w * gv.w;
        o4[idx] = o;
    }
}

extern "C" void kernel_launch(void* const* d_in, const int* in_sizes, int n_in,
                              void* d_out, int out_size, void* d_ws, size_t ws_size,
                              hipStream_t stream) {
    const float* x = (const float*)d_in[0];
    float* out = (float*)d_out;
    max_kernel<<<B_DIM * 4, 256, 0, stream>>>(x, out);
    softmax_kernel<<<B_DIM, 256, 0, stream>>>(out);
    mul_kernel<<<B_DIM * 4, 512, 0, stream>>>(x, out);
}